// Round 18
// baseline (79.445 us; speedup 1.0000x reference)
//
#include <hip/hip_runtime.h>
#include <stdint.h>

// Problem constants
#define NN 16384                  // sampled points per batch (h*w)
#define HW 65536                  // H*W
#define OUT_HALF (2 * NN * 128)   // one tuple element, flat floats
// MLP: 67 -> 64 -> 64 -> 128 (BN folded), maxpool over K=32 neighbors.
//
// Round-18 = round-17 (78.6 us, occ 75%, absmax 1.22e-4) with ONE change:
// L2 processes its two output columns j=0/j=1 SEQUENTIALLY with a single
// f32x16 accumulator. r17's launch_bounds(512,8) forced combined regs <=64
// and the old L2 live-set (gh 16 + acc2[2] 32 + w 8) spilled ~16B/thread:
// WRITE_SIZE 32.8->65.5 MB, FETCH +24 MB. Sequential j drops L2 live-set to
// ~40 regs; the 4-deep dependent MFMA chain is hidden at 24 waves/CU.
// Everything else byte-identical to r17 (32 KiB hi-only LDS image -> 4
// blocks/CU; launch_bounds(512,8) -> 8 waves/SIMD; 1-pass full-bf16 MFMA;
// bias/X0 global).
//
// Dataflow (m74/m101-verified maps):
//   L0/L1 operand-swapped (A=W, B=act) -> C/D col = lane&31 = neighbor.
//   Transitions in-register: relu -> cvt_pk -> permlane32_swap.
//   L2 normal (A=act, B=W); maxpool = 16 fmax + xor(32); kh halves store the
//   two tuple copies.
//
// Fragment maps (gfx950 32x32x16 bf16):
//   A: row = lane&31, k = 8*(lane>>5)+e ;  B: col = lane&31, same k
//   C/D: col = lane&31, row = (rg&3) + 8*(rg>>2) + 4*(lane>>5)

typedef __attribute__((ext_vector_type(8)))  short bf16x8;
typedef __attribute__((ext_vector_type(16))) float f32x16;

// ws layout, uint16 units (IDENTICAL to rounds 11/14/16/17):
//  L0 hi (kt 0..3) @ 0      [4 kt][2 tile][64 lane][8 e] = 4096
//  L0 lo           @ 4096   (unread)
//  L1 hi           @ 8192
//  L1 lo           @ 12288  (unread)
//  L2 hi           @ 16384
//  L2 lo           @ 24576  (unread)
//  L0 xyz-step hi  @ 32768  [2 tile][64][8] = 1024   (global-read)
//  L0 xyz-step lo  @ 33792  (unread)
//  bias            @ 34816  f32[256]                  (global-read)
#define WS_L0H 0
#define WS_L0L 4096
#define WS_L1H 8192
#define WS_L1L 12288
#define WS_L2H 16384
#define WS_L2L 24576
#define WS_X0H 32768
#define WS_X0L 33792
#define WS_BIAS 34816

// LDS compacted image (hi-only), uint16 units:
#define LDS_L0H 0                 // 4096
#define LDS_L1H 4096              // 4096
#define LDS_L2H 8192              // 8192
#define LDS_U16 16384             // 32 KiB

__device__ inline uint16_t f32_to_bf16_rne(float x) {
    uint32_t u = __float_as_uint(x);
    uint32_t r = (u + 0x7FFFu + ((u >> 16) & 1u)) >> 16;
    return (uint16_t)r;
}
__device__ inline float bf16_hi_f32(uint16_t h) {
    return __uint_as_float(((uint32_t)h) << 16);
}
__device__ inline void split2(float v, uint16_t* hi, uint16_t* lo) {
    uint16_t h = f32_to_bf16_rne(v);
    *hi = h;
    *lo = f32_to_bf16_rne(v - bf16_hi_f32(h));
}

// ---------------- weight prep (runs once per launch, tiny) ----------------
// BYTE-IDENTICAL to rounds 11/14/16/17.
__global__ void prep_weights(
    const float* __restrict__ W0, const float* __restrict__ b0,
    const float* __restrict__ g0, const float* __restrict__ be0,
    const float* __restrict__ W1, const float* __restrict__ b1,
    const float* __restrict__ g1, const float* __restrict__ be1,
    const float* __restrict__ W2, const float* __restrict__ b2,
    const float* __restrict__ g2, const float* __restrict__ be2,
    uint16_t* __restrict__ ws)
{
    const int tid = blockIdx.x * blockDim.x + threadIdx.x;
    const int nth = gridDim.x * blockDim.x;

    for (int i = tid; i < 4096; i += nth) {
        int e = i & 7, lane = (i >> 3) & 63, nt = (i >> 9) & 1, kt = i >> 10;
        int k = kt * 16 + 8 * (lane >> 5) + e;
        int n = nt * 32 + (lane & 31);
        float v = W0[(3 + k) * 64 + n] * g0[n];
        uint16_t hi, lo; split2(v, &hi, &lo);
        ws[WS_L0H + i] = hi; ws[WS_L0L + i] = lo;
    }
    for (int i = tid; i < 1024; i += nth) {
        int e = i & 7, lane = (i >> 3) & 63, nt = i >> 9;
        int k = 64 + 8 * (lane >> 5) + e;
        int n = nt * 32 + (lane & 31);
        float v = (k < 67) ? W0[(k - 64) * 64 + n] * g0[n] : 0.f;
        uint16_t hi, lo; split2(v, &hi, &lo);
        ws[WS_X0H + i] = hi; ws[WS_X0L + i] = lo;
    }
    for (int i = tid; i < 4096; i += nth) {
        int e = i & 7, lane = (i >> 3) & 63, nt = (i >> 9) & 1, kt = i >> 10;
        int k = kt * 16 + 8 * (lane >> 5) + e;
        int n = nt * 32 + (lane & 31);
        float v = W1[k * 64 + n] * g1[n];
        uint16_t hi, lo; split2(v, &hi, &lo);
        ws[WS_L1H + i] = hi; ws[WS_L1L + i] = lo;
    }
    for (int i = tid; i < 8192; i += nth) {
        int e = i & 7, lane = (i >> 3) & 63, nt = (i >> 9) & 3, kt = i >> 11;
        int k = kt * 16 + 8 * (lane >> 5) + e;
        int n = nt * 32 + (lane & 31);
        float v = W2[k * 128 + n] * g2[n];
        uint16_t hi, lo; split2(v, &hi, &lo);
        ws[WS_L2H + i] = hi; ws[WS_L2L + i] = lo;
    }
    float* bias = (float*)(ws + WS_BIAS);
    for (int i = tid; i < 64; i += nth)  bias[i]       = b0[i] * g0[i] + be0[i];
    for (int i = tid; i < 64; i += nth)  bias[64 + i]  = b1[i] * g1[i] + be1[i];
    for (int i = tid; i < 128; i += nth) bias[128 + i] = b2[i] * g2[i] + be2[i];
}

// ---------------- main kernel helpers ----------------
__device__ inline uint32_t cvt_pk_bf16(float a, float b) {
    uint32_t r;
    asm("v_cvt_pk_bf16_f32 %0, %1, %2" : "=v"(r) : "v"(a), "v"(b));
    return r;
}

union frag_u { uint32_t w[4]; bf16x8 v; };

// convert 8 f32 -> bf16x8 (RNE) via packed converts
__device__ inline bf16x8 cvt8(const float* f) {
    frag_u H;
    #pragma unroll
    for (int p2 = 0; p2 < 4; ++p2)
        H.w[p2] = cvt_pk_bf16(f[2 * p2], f[2 * p2 + 1]);
    return H.v;
}

// relu + bf16 convert + permlane32_swap assembly of next layer's K-fragments.
__device__ inline void transition(const f32x16* acc, bf16x8* fh) {
    #pragma unroll
    for (int mt = 0; mt < 2; ++mt) {
        uint32_t H[8];
        #pragma unroll
        for (int w = 0; w < 8; ++w) {
            float a = fmaxf(acc[mt][2 * w],     0.f);
            float b = fmaxf(acc[mt][2 * w + 1], 0.f);
            H[w] = cvt_pk_bf16(a, b);
        }
        #pragma unroll
        for (int ktL = 0; ktL < 2; ++ktL) {
            uint32_t a0 = H[4 * ktL + 0], b0 = H[4 * ktL + 2];
            uint32_t a1 = H[4 * ktL + 1], b1 = H[4 * ktL + 3];
            asm("v_permlane32_swap_b32 %0, %1" : "+v"(a0), "+v"(b0));
            asm("v_permlane32_swap_b32 %0, %1" : "+v"(a1), "+v"(b1));
            frag_u F; F.w[0] = a0; F.w[1] = a1; F.w[2] = b0; F.w[3] = b1;
            fh[mt * 2 + ktL] = F.v;
        }
    }
}

__global__ __launch_bounds__(512, 8)
void pointnet_mfma(
    const float* __restrict__ xyz_proj,      // [B, H*W, 3]
    const float* __restrict__ points_proj,   // [B, H*W, 64]
    const float* __restrict__ xyz_sampled,   // [B, N, 3]
    const int*   __restrict__ nidx,          // [B, N, 32]
    const float* __restrict__ vmask,         // [B, N, 32, 1]
    const uint16_t* __restrict__ wf,
    float* __restrict__ out)
{
    __shared__ __align__(16) uint16_t slds[LDS_U16];   // 32 KiB hi-only image

    // ---- cooperative fill: 3 disjoint hi chunks -> contiguous LDS ----
    {
        const uint4* src = (const uint4*)wf;
        uint4* dst = (uint4*)slds;
        #pragma unroll
        for (int j = 0; j < 4; ++j) {
            int i = threadIdx.x + j * 512;
            int s = (i < 512) ? i : (i < 1024 ? i + 512 : i + 1024);
            dst[i] = src[s];
        }
    }
    __syncthreads();   // only barrier; waves independent afterwards

    // XCD-aware bijective swizzle (grid 4096, 8 XCDs, 512 blocks per XCD)
    const int bid = blockIdx.x;
    const int swz = (bid & 7) * 512 + (bid >> 3);

    const int t    = threadIdx.x & 63;
    const int widx = threadIdx.x >> 6;       // 0..7
    const int p    = swz * 8 + widx;          // point id in [0, 2*NN)
    const int rb   = (p >> 14) << 16;          // b * HW

    const int r  = t & 31;   // this lane's neighbor (col) all the way through
    const int kh = t >> 5;   // k-half selector

    const bf16x8* L0h = (const bf16x8*)(slds + LDS_L0H);
    const bf16x8* L1h = (const bf16x8*)(slds + LDS_L1H);
    const bf16x8* L2h = (const bf16x8*)(slds + LDS_L2H);
    const bf16x8* X0h = (const bf16x8*)(wf + WS_X0H);   // xyz step: global
    const float*  bias = (const float*)(wf + WS_BIAS);  // bias: global

    // ---- per-neighbor scalars (each lane: its own neighbor) ----
    const int   idx = nidx[(size_t)p * 32 + r];
    const float m   = vmask[(size_t)p * 32 + r];
    float xd0, xd1, xd2;
    {
        const float* xs = xyz_proj + (size_t)(rb + idx) * 3;
        const float* ns = xyz_sampled + (size_t)p * 3;
        xd0 = xs[0] * m - ns[0];
        xd1 = xs[1] * m - ns[1];
        xd2 = xs[2] * m - ns[2];
    }
    const float* rowp = points_proj + (size_t)(rb + idx) * 64 + 8 * kh;

    // ---- layer 0: K = 64 (channels) + 3 (xyz) -> 64, swapped (W=A) ----
    f32x16 acc0[2];
    #pragma unroll
    for (int mt = 0; mt < 2; ++mt)
        #pragma unroll
        for (int q = 0; q < 4; ++q) {
            float4 bq = *(const float4*)(bias + mt * 32 + 4 * kh + 8 * q);
            acc0[mt][4 * q + 0] = bq.x; acc0[mt][4 * q + 1] = bq.y;
            acc0[mt][4 * q + 2] = bq.z; acc0[mt][4 * q + 3] = bq.w;
        }
    #pragma unroll
    for (int kt = 0; kt < 4; ++kt) {
        bf16x8 w0 = L0h[(kt * 2 + 0) * 64 + t];
        bf16x8 w1 = L0h[(kt * 2 + 1) * 64 + t];
        float f[8];
        *(float4*)&f[0] = ((const float4*)(rowp + kt * 16))[0];
        *(float4*)&f[4] = ((const float4*)(rowp + kt * 16))[1];
        #pragma unroll
        for (int e = 0; e < 8; ++e) f[e] *= m;
        bf16x8 bh = cvt8(f);
        acc0[0] = __builtin_amdgcn_mfma_f32_32x32x16_bf16(w0, bh, acc0[0], 0, 0, 0);
        acc0[1] = __builtin_amdgcn_mfma_f32_32x32x16_bf16(w1, bh, acc0[1], 0, 0, 0);
    }
    {   // xyz k-step (k 64..66 live in kh==0 lanes, e<3); weights from global
        bf16x8 w0 = X0h[0 * 64 + t];
        bf16x8 w1 = X0h[1 * 64 + t];
        const bool lo32 = (kh == 0);
        float f[8] = { lo32 ? xd0 : 0.f, lo32 ? xd1 : 0.f, lo32 ? xd2 : 0.f,
                       0.f, 0.f, 0.f, 0.f, 0.f };
        bf16x8 bh = cvt8(f);
        acc0[0] = __builtin_amdgcn_mfma_f32_32x32x16_bf16(w0, bh, acc0[0], 0, 0, 0);
        acc0[1] = __builtin_amdgcn_mfma_f32_32x32x16_bf16(w1, bh, acc0[1], 0, 0, 0);
    }

    // ---- transition 1: in-register relu+cvt+swap -> L1 B-fragments ----
    bf16x8 fh[4];
    transition(acc0, fh);

    // ---- layer 1: 64 -> 64, swapped (W=A) ----
    f32x16 acc1[2];
    #pragma unroll
    for (int mt = 0; mt < 2; ++mt)
        #pragma unroll
        for (int q = 0; q < 4; ++q) {
            float4 bq = *(const float4*)(bias + 64 + mt * 32 + 4 * kh + 8 * q);
            acc1[mt][4 * q + 0] = bq.x; acc1[mt][4 * q + 1] = bq.y;
            acc1[mt][4 * q + 2] = bq.z; acc1[mt][4 * q + 3] = bq.w;
        }
    #pragma unroll
    for (int kt = 0; kt < 4; ++kt) {
        bf16x8 w0 = L1h[(kt * 2 + 0) * 64 + t];
        bf16x8 w1 = L1h[(kt * 2 + 1) * 64 + t];
        acc1[0] = __builtin_amdgcn_mfma_f32_32x32x16_bf16(w0, fh[kt], acc1[0], 0, 0, 0);
        acc1[1] = __builtin_amdgcn_mfma_f32_32x32x16_bf16(w1, fh[kt], acc1[1], 0, 0, 0);
    }

    // ---- transition 2 -> L2 A-fragments (same per-lane layout) ----
    bf16x8 gh[4];
    transition(acc1, gh);

    // ---- layer 2: 64 -> 128, normal (act=A); j SEQUENTIAL (single acc) ----
    #pragma unroll
    for (int half = 0; half < 2; ++half) {
        #pragma unroll
        for (int j = 0; j < 2; ++j) {
            f32x16 acc2;
            const float bb = bias[128 + (half * 2 + j) * 32 + r];
            #pragma unroll
            for (int i = 0; i < 16; ++i) acc2[i] = bb;
            #pragma unroll
            for (int kt = 0; kt < 4; ++kt) {
                bf16x8 w = L2h[(kt * 4 + half * 2 + j) * 64 + t];
                acc2 = __builtin_amdgcn_mfma_f32_32x32x16_bf16(gh[kt], w, acc2, 0, 0, 0);
            }
            float v = acc2[0];
            #pragma unroll
            for (int g = 1; g < 16; ++g) v = fmaxf(v, acc2[g]);
            v = fmaxf(v, __shfl_xor(v, 32));   // merge kh halves
            v = fmaxf(v, 0.f);                 // relu commutes with max
            // kh=0 lanes store tuple copy 0, kh=1 lanes store copy 1
            size_t o = (size_t)p * 128 + (half * 2 + j) * 32 + r
                     + (size_t)kh * OUT_HALF;
            out[o] = v;
        }
    }
}

extern "C" void kernel_launch(void* const* d_in, const int* in_sizes, int n_in,
                              void* d_out, int out_size, void* d_ws, size_t ws_size,
                              hipStream_t stream) {
    const float* xyz_proj    = (const float*)d_in[0];
    const float* points_proj = (const float*)d_in[1];
    const float* xyz_sampled = (const float*)d_in[2];
    const int*   neighbor_idx= (const int*)  d_in[3];
    const float* valid_mask  = (const float*)d_in[4];
    const float* W0 = (const float*)d_in[5];
    const float* b0 = (const float*)d_in[6];
    const float* g0 = (const float*)d_in[7];
    const float* be0= (const float*)d_in[8];
    const float* W1 = (const float*)d_in[9];
    const float* b1 = (const float*)d_in[10];
    const float* g1 = (const float*)d_in[11];
    const float* be1= (const float*)d_in[12];
    const float* W2 = (const float*)d_in[13];
    const float* b2 = (const float*)d_in[14];
    const float* g2 = (const float*)d_in[15];
    const float* be2= (const float*)d_in[16];

    uint16_t* ws = (uint16_t*)d_ws;

    prep_weights<<<64, 256, 0, stream>>>(W0, b0, g0, be0,
                                         W1, b1, g1, be1,
                                         W2, b2, g2, be2, ws);

    // 32768 points: 1 per wave, 8 waves per block -> 4096 blocks
    pointnet_mfma<<<4096, 512, 0, stream>>>(
        xyz_proj, points_proj, xyz_sampled, neighbor_idx, valid_mask,
        ws, (float*)d_out);
}

// Round 19
// 74.613 us; speedup vs baseline: 1.0647x; 1.0647x over previous
//
#include <hip/hip_runtime.h>
#include <stdint.h>

// Problem constants
#define NN 16384                  // sampled points per batch (h*w)
#define HW 65536                  // H*W
#define OUT_HALF (2 * NN * 128)   // one tuple element, flat floats
// MLP: 67 -> 64 -> 64 -> 128 (BN folded), maxpool over K=32 neighbors.
//
// Round-19 = round-17/18 with ALL layers processed sequential-mt (single
// f32x16 accumulator live at any time). r17/18 spilled under the forced
// 64-combined-reg budget because acc[2]=32 AGPRs left only 32 arch VGPRs
// (unified file): WRITE_SIZE 65.5 MB. Sequential-mt halves the AGPR
// footprint to 16; L0 activations load ONCE into bh[4] (16 arch regs,
// reused by both mt passes -- no extra gather traffic); each pass's acc is
// converted to bf16 K-fragments (trans1) immediately, then dies.
// Peak combined live-set ~60 <= 64 -> no scratch (WRITE back to 33 MB).
// Everything else identical to r17: 32 KiB hi-only LDS image (4 blocks/CU),
// launch_bounds(512,8) (32-wave/CU cap), 1-pass full-bf16 MFMA, bias/X0
// global, XCD swizzle, grid 4096.
//
// Dataflow (m74/m101-verified maps):
//   L0/L1 operand-swapped (A=W, B=act) -> C/D col = lane&31 = neighbor.
//   Transitions in-register: relu -> cvt_pk -> permlane32_swap.
//   L2 normal (A=act, B=W); maxpool = 16 fmax + xor(32); kh halves store the
//   two tuple copies.
//
// Fragment maps (gfx950 32x32x16 bf16):
//   A: row = lane&31, k = 8*(lane>>5)+e ;  B: col = lane&31, same k
//   C/D: col = lane&31, row = (rg&3) + 8*(rg>>2) + 4*(lane>>5)

typedef __attribute__((ext_vector_type(8)))  short bf16x8;
typedef __attribute__((ext_vector_type(16))) float f32x16;

// ws layout, uint16 units (IDENTICAL to rounds 11/14/16/17/18):
#define WS_L0H 0
#define WS_L0L 4096
#define WS_L1H 8192
#define WS_L1L 12288
#define WS_L2H 16384
#define WS_L2L 24576
#define WS_X0H 32768
#define WS_X0L 33792
#define WS_BIAS 34816

// LDS compacted image (hi-only), uint16 units:
#define LDS_L0H 0                 // 4096
#define LDS_L1H 4096              // 4096
#define LDS_L2H 8192              // 8192
#define LDS_U16 16384             // 32 KiB

__device__ inline uint16_t f32_to_bf16_rne(float x) {
    uint32_t u = __float_as_uint(x);
    uint32_t r = (u + 0x7FFFu + ((u >> 16) & 1u)) >> 16;
    return (uint16_t)r;
}
__device__ inline float bf16_hi_f32(uint16_t h) {
    return __uint_as_float(((uint32_t)h) << 16);
}
__device__ inline void split2(float v, uint16_t* hi, uint16_t* lo) {
    uint16_t h = f32_to_bf16_rne(v);
    *hi = h;
    *lo = f32_to_bf16_rne(v - bf16_hi_f32(h));
}

// ---------------- weight prep (runs once per launch, tiny) ----------------
// BYTE-IDENTICAL to rounds 11/14/16/17/18.
__global__ void prep_weights(
    const float* __restrict__ W0, const float* __restrict__ b0,
    const float* __restrict__ g0, const float* __restrict__ be0,
    const float* __restrict__ W1, const float* __restrict__ b1,
    const float* __restrict__ g1, const float* __restrict__ be1,
    const float* __restrict__ W2, const float* __restrict__ b2,
    const float* __restrict__ g2, const float* __restrict__ be2,
    uint16_t* __restrict__ ws)
{
    const int tid = blockIdx.x * blockDim.x + threadIdx.x;
    const int nth = gridDim.x * blockDim.x;

    for (int i = tid; i < 4096; i += nth) {
        int e = i & 7, lane = (i >> 3) & 63, nt = (i >> 9) & 1, kt = i >> 10;
        int k = kt * 16 + 8 * (lane >> 5) + e;
        int n = nt * 32 + (lane & 31);
        float v = W0[(3 + k) * 64 + n] * g0[n];
        uint16_t hi, lo; split2(v, &hi, &lo);
        ws[WS_L0H + i] = hi; ws[WS_L0L + i] = lo;
    }
    for (int i = tid; i < 1024; i += nth) {
        int e = i & 7, lane = (i >> 3) & 63, nt = i >> 9;
        int k = 64 + 8 * (lane >> 5) + e;
        int n = nt * 32 + (lane & 31);
        float v = (k < 67) ? W0[(k - 64) * 64 + n] * g0[n] : 0.f;
        uint16_t hi, lo; split2(v, &hi, &lo);
        ws[WS_X0H + i] = hi; ws[WS_X0L + i] = lo;
    }
    for (int i = tid; i < 4096; i += nth) {
        int e = i & 7, lane = (i >> 3) & 63, nt = (i >> 9) & 1, kt = i >> 10;
        int k = kt * 16 + 8 * (lane >> 5) + e;
        int n = nt * 32 + (lane & 31);
        float v = W1[k * 64 + n] * g1[n];
        uint16_t hi, lo; split2(v, &hi, &lo);
        ws[WS_L1H + i] = hi; ws[WS_L1L + i] = lo;
    }
    for (int i = tid; i < 8192; i += nth) {
        int e = i & 7, lane = (i >> 3) & 63, nt = (i >> 9) & 3, kt = i >> 11;
        int k = kt * 16 + 8 * (lane >> 5) + e;
        int n = nt * 32 + (lane & 31);
        float v = W2[k * 128 + n] * g2[n];
        uint16_t hi, lo; split2(v, &hi, &lo);
        ws[WS_L2H + i] = hi; ws[WS_L2L + i] = lo;
    }
    float* bias = (float*)(ws + WS_BIAS);
    for (int i = tid; i < 64; i += nth)  bias[i]       = b0[i] * g0[i] + be0[i];
    for (int i = tid; i < 64; i += nth)  bias[64 + i]  = b1[i] * g1[i] + be1[i];
    for (int i = tid; i < 128; i += nth) bias[128 + i] = b2[i] * g2[i] + be2[i];
}

// ---------------- main kernel helpers ----------------
__device__ inline uint32_t cvt_pk_bf16(float a, float b) {
    uint32_t r;
    asm("v_cvt_pk_bf16_f32 %0, %1, %2" : "=v"(r) : "v"(a), "v"(b));
    return r;
}

union frag_u { uint32_t w[4]; bf16x8 v; };

// convert 8 f32 -> bf16x8 (RNE) via packed converts
__device__ inline bf16x8 cvt8(const float* f) {
    frag_u H;
    #pragma unroll
    for (int p2 = 0; p2 < 4; ++p2)
        H.w[p2] = cvt_pk_bf16(f[2 * p2], f[2 * p2 + 1]);
    return H.v;
}

// relu + bf16 convert + permlane32_swap for ONE mt accumulator ->
// two kt-indexed K-fragments. (Same math as r16-18's transition, per-mt.)
__device__ inline void trans1(const f32x16& acc, bf16x8* f0, bf16x8* f1) {
    uint32_t H[8];
    #pragma unroll
    for (int w = 0; w < 8; ++w) {
        float a = fmaxf(acc[2 * w],     0.f);
        float b = fmaxf(acc[2 * w + 1], 0.f);
        H[w] = cvt_pk_bf16(a, b);
    }
    {
        uint32_t a0 = H[0], b0 = H[2], a1 = H[1], b1 = H[3];
        asm("v_permlane32_swap_b32 %0, %1" : "+v"(a0), "+v"(b0));
        asm("v_permlane32_swap_b32 %0, %1" : "+v"(a1), "+v"(b1));
        frag_u F; F.w[0] = a0; F.w[1] = a1; F.w[2] = b0; F.w[3] = b1;
        *f0 = F.v;
    }
    {
        uint32_t a0 = H[4], b0 = H[6], a1 = H[5], b1 = H[7];
        asm("v_permlane32_swap_b32 %0, %1" : "+v"(a0), "+v"(b0));
        asm("v_permlane32_swap_b32 %0, %1" : "+v"(a1), "+v"(b1));
        frag_u F; F.w[0] = a0; F.w[1] = a1; F.w[2] = b0; F.w[3] = b1;
        *f1 = F.v;
    }
}

__global__ __launch_bounds__(512, 8)
void pointnet_mfma(
    const float* __restrict__ xyz_proj,      // [B, H*W, 3]
    const float* __restrict__ points_proj,   // [B, H*W, 64]
    const float* __restrict__ xyz_sampled,   // [B, N, 3]
    const int*   __restrict__ nidx,          // [B, N, 32]
    const float* __restrict__ vmask,         // [B, N, 32, 1]
    const uint16_t* __restrict__ wf,
    float* __restrict__ out)
{
    __shared__ __align__(16) uint16_t slds[LDS_U16];   // 32 KiB hi-only image

    // ---- cooperative fill: 3 disjoint hi chunks -> contiguous LDS ----
    {
        const uint4* src = (const uint4*)wf;
        uint4* dst = (uint4*)slds;
        #pragma unroll
        for (int j = 0; j < 4; ++j) {
            int i = threadIdx.x + j * 512;
            int s = (i < 512) ? i : (i < 1024 ? i + 512 : i + 1024);
            dst[i] = src[s];
        }
    }
    __syncthreads();   // only barrier; waves independent afterwards

    // XCD-aware bijective swizzle (grid 4096, 8 XCDs, 512 blocks per XCD)
    const int bid = blockIdx.x;
    const int swz = (bid & 7) * 512 + (bid >> 3);

    const int t    = threadIdx.x & 63;
    const int widx = threadIdx.x >> 6;       // 0..7
    const int p    = swz * 8 + widx;          // point id in [0, 2*NN)
    const int rb   = (p >> 14) << 16;          // b * HW

    const int r  = t & 31;   // this lane's neighbor (col) all the way through
    const int kh = t >> 5;   // k-half selector

    const bf16x8* L0h = (const bf16x8*)(slds + LDS_L0H);
    const bf16x8* L1h = (const bf16x8*)(slds + LDS_L1H);
    const bf16x8* L2h = (const bf16x8*)(slds + LDS_L2H);
    const bf16x8* X0h = (const bf16x8*)(wf + WS_X0H);   // xyz step: global
    const float*  bias = (const float*)(wf + WS_BIAS);  // bias: global

    // ---- per-neighbor scalars (each lane: its own neighbor) ----
    const int   idx = nidx[(size_t)p * 32 + r];
    const float m   = vmask[(size_t)p * 32 + r];
    float xd0, xd1, xd2;
    {
        const float* xs = xyz_proj + (size_t)(rb + idx) * 3;
        const float* ns = xyz_sampled + (size_t)p * 3;
        xd0 = xs[0] * m - ns[0];
        xd1 = xs[1] * m - ns[1];
        xd2 = xs[2] * m - ns[2];
    }
    const float* rowp = points_proj + (size_t)(rb + idx) * 64 + 8 * kh;

    // ---- gather activations ONCE into bh[4] (reused by both mt passes) ----
    bf16x8 bh[4];
    #pragma unroll
    for (int kt = 0; kt < 4; ++kt) {
        float f[8];
        *(float4*)&f[0] = ((const float4*)(rowp + kt * 16))[0];
        *(float4*)&f[4] = ((const float4*)(rowp + kt * 16))[1];
        #pragma unroll
        for (int e = 0; e < 8; ++e) f[e] *= m;
        bh[kt] = cvt8(f);
    }

    // ---- layer 0 (sequential mt, single acc) -> fh[4] ----
    bf16x8 fh[4];
    #pragma unroll
    for (int mt = 0; mt < 2; ++mt) {
        f32x16 acc;
        #pragma unroll
        for (int q = 0; q < 4; ++q) {
            float4 bq = *(const float4*)(bias + mt * 32 + 4 * kh + 8 * q);
            acc[4 * q + 0] = bq.x; acc[4 * q + 1] = bq.y;
            acc[4 * q + 2] = bq.z; acc[4 * q + 3] = bq.w;
        }
        #pragma unroll
        for (int kt = 0; kt < 4; ++kt) {
            bf16x8 w = L0h[(kt * 2 + mt) * 64 + t];
            acc = __builtin_amdgcn_mfma_f32_32x32x16_bf16(w, bh[kt], acc, 0, 0, 0);
        }
        {   // xyz k-step (k 64..66 live in kh==0 lanes, e<3); transient frag
            bf16x8 w = X0h[mt * 64 + t];
            const bool lo32 = (kh == 0);
            float f[8] = { lo32 ? xd0 : 0.f, lo32 ? xd1 : 0.f, lo32 ? xd2 : 0.f,
                           0.f, 0.f, 0.f, 0.f, 0.f };
            bf16x8 bx = cvt8(f);
            acc = __builtin_amdgcn_mfma_f32_32x32x16_bf16(w, bx, acc, 0, 0, 0);
        }
        trans1(acc, &fh[mt * 2 + 0], &fh[mt * 2 + 1]);
    }

    // ---- layer 1 (sequential mt, single acc) -> gh[4] ----
    bf16x8 gh[4];
    #pragma unroll
    for (int mt = 0; mt < 2; ++mt) {
        f32x16 acc;
        #pragma unroll
        for (int q = 0; q < 4; ++q) {
            float4 bq = *(const float4*)(bias + 64 + mt * 32 + 4 * kh + 8 * q);
            acc[4 * q + 0] = bq.x; acc[4 * q + 1] = bq.y;
            acc[4 * q + 2] = bq.z; acc[4 * q + 3] = bq.w;
        }
        #pragma unroll
        for (int kt = 0; kt < 4; ++kt) {
            bf16x8 w = L1h[(kt * 2 + mt) * 64 + t];
            acc = __builtin_amdgcn_mfma_f32_32x32x16_bf16(w, fh[kt], acc, 0, 0, 0);
        }
        trans1(acc, &gh[mt * 2 + 0], &gh[mt * 2 + 1]);
    }

    // ---- layer 2: 64 -> 128, normal (act=A); fully sequential ----
    #pragma unroll
    for (int half = 0; half < 2; ++half) {
        #pragma unroll
        for (int j = 0; j < 2; ++j) {
            f32x16 acc;
            const float bb = bias[128 + (half * 2 + j) * 32 + r];
            #pragma unroll
            for (int i = 0; i < 16; ++i) acc[i] = bb;
            #pragma unroll
            for (int kt = 0; kt < 4; ++kt) {
                bf16x8 w = L2h[(kt * 4 + half * 2 + j) * 64 + t];
                acc = __builtin_amdgcn_mfma_f32_32x32x16_bf16(gh[kt], w, acc, 0, 0, 0);
            }
            float v = acc[0];
            #pragma unroll
            for (int g = 1; g < 16; ++g) v = fmaxf(v, acc[g]);
            v = fmaxf(v, __shfl_xor(v, 32));   // merge kh halves
            v = fmaxf(v, 0.f);                 // relu commutes with max
            // kh=0 lanes store tuple copy 0, kh=1 lanes store copy 1
            size_t o = (size_t)p * 128 + (half * 2 + j) * 32 + r
                     + (size_t)kh * OUT_HALF;
            out[o] = v;
        }
    }
}

extern "C" void kernel_launch(void* const* d_in, const int* in_sizes, int n_in,
                              void* d_out, int out_size, void* d_ws, size_t ws_size,
                              hipStream_t stream) {
    const float* xyz_proj    = (const float*)d_in[0];
    const float* points_proj = (const float*)d_in[1];
    const float* xyz_sampled = (const float*)d_in[2];
    const int*   neighbor_idx= (const int*)  d_in[3];
    const float* valid_mask  = (const float*)d_in[4];
    const float* W0 = (const float*)d_in[5];
    const float* b0 = (const float*)d_in[6];
    const float* g0 = (const float*)d_in[7];
    const float* be0= (const float*)d_in[8];
    const float* W1 = (const float*)d_in[9];
    const float* b1 = (const float*)d_in[10];
    const float* g1 = (const float*)d_in[11];
    const float* be1= (const float*)d_in[12];
    const float* W2 = (const float*)d_in[13];
    const float* b2 = (const float*)d_in[14];
    const float* g2 = (const float*)d_in[15];
    const float* be2= (const float*)d_in[16];

    uint16_t* ws = (uint16_t*)d_ws;

    prep_weights<<<64, 256, 0, stream>>>(W0, b0, g0, be0,
                                         W1, b1, g1, be1,
                                         W2, b2, g2, be2, ws);

    // 32768 points: 1 per wave, 8 waves per block -> 4096 blocks
    pointnet_mfma<<<4096, 512, 0, stream>>>(
        xyz_proj, points_proj, xyz_sampled, neighbor_idx, valid_mask,
        ws, (float*)d_out);
}